// Round 2
// baseline (16236.588 us; speedup 1.0000x reference)
//
#include <hip/hip_runtime.h>

typedef short  sh8  __attribute__((ext_vector_type(8)));
typedef float  f32x4 __attribute__((ext_vector_type(4)));
typedef ushort ush4 __attribute__((ext_vector_type(4)));

#define TS 1024
#define BB 64
#define HH 512

// d_out element offsets (fp32 elements): output [1024][64][1024], h [2][64][1024], c [2][64][1024]
#define HOFF 67108864ull
#define HC_DELTA 131072ull

static __device__ __forceinline__ float sigm(float x){ return 1.f/(1.f+__expf(-x)); }
static __device__ __forceinline__ float tanh_(float x){ return 1.f - 2.f/(__expf(2.f*x)+1.f); }
static __device__ __forceinline__ ushort f2bf(float f){
  unsigned u = __float_as_uint(f);
  u += 0x7fffu + ((u>>16)&1u);   // RNE
  return (ushort)(u>>16);
}

// ---- prep: fp32 -> bf16 conversions into ws ----
__global__ __launch_bounds__(256) void cvt_w(
    const float* __restrict__ p0, const float* __restrict__ p1,
    const float* __restrict__ p2, const float* __restrict__ p3,
    const float* __restrict__ p4, const float* __restrict__ p5,
    const float* __restrict__ p6, const float* __restrict__ p7,
    ushort* __restrict__ wb)
{
  const unsigned gid = blockIdx.x*256 + threadIdx.x;   // 2^21 float4s total
  const unsigned m = gid >> 18;                        // matrix index 0..7
  const unsigned o = gid & 0x3FFFFu;                   // float4 offset in matrix
  const float* src;
  switch(m){
    case 0: src=p0; break; case 1: src=p1; break; case 2: src=p2; break; case 3: src=p3; break;
    case 4: src=p4; break; case 5: src=p5; break; case 6: src=p6; break; default: src=p7; break;
  }
  float4 f = *(const float4*)(src + (size_t)o*4);
  ush4 r; r.x=f2bf(f.x); r.y=f2bf(f.y); r.z=f2bf(f.z); r.w=f2bf(f.w);
  *(ush4*)(wb + ((size_t)m<<20) + (size_t)o*4) = r;
}

__global__ __launch_bounds__(256) void cvt_x(
    const float* __restrict__ x, ushort* __restrict__ xb)
{
  const unsigned gid = blockIdx.x*256 + threadIdx.x;   // 2^23 float4s
  float4 f = *(const float4*)(x + (size_t)gid*4);
  ush4 r; r.x=f2bf(f.x); r.y=f2bf(f.y); r.z=f2bf(f.z); r.w=f2bf(f.w);
  *(ush4*)(xb + (size_t)gid*4) = r;
}

static __device__ __forceinline__ sh8 ld_cvt8(const float* p){
  float4 f0 = *(const float4*)p;
  float4 f1 = *(const float4*)(p+4);
  sh8 r;
  r[0]=(short)f2bf(f0.x); r[1]=(short)f2bf(f0.y); r[2]=(short)f2bf(f0.z); r[3]=(short)f2bf(f0.w);
  r[4]=(short)f2bf(f1.x); r[5]=(short)f2bf(f1.y); r[6]=(short)f2bf(f1.z); r[7]=(short)f2bf(f1.w);
  return r;
}

// Pipeline slot s in [0,1024]:
//   group 0: layer0 fwd step s | group 1: layer0 bwd scan step s (x[1023-s])
//   group 2: layer1 fwd step s-1 | group 3: layer1 bwd scan step s-1
// h double-buffers (bf16) + c state (fp32) in ws. XBF: x pre-converted to bf16 in ws.
template<bool XBF>
__global__ __launch_bounds__(256) void lstm_slot(
    const float* __restrict__ xf, const ushort* __restrict__ xb,
    const ushort* __restrict__ wb,
    float* __restrict__ out, float* __restrict__ c_ws, ushort* __restrict__ h_ws,
    int s)
{
  const int group = blockIdx.x >> 6;   // 0:L0F 1:L0B 2:L1F 3:L1B
  const int w     = blockIdx.x & 63;   // owns h-cols [8w, 8w+8)
  if (group >= 2 && s == 0) return;
  if (group <  2 && s == TS) return;

  const int lane = threadIdx.x & 63;
  const int wv   = threadIdx.x >> 6;
  const int n    = lane & 15;
  const int q    = lane >> 4;

  // wb matrix order: wihf0, whhf0, wihf1, whhf1, wihb0, whhb0, wihb1, whhb1
  int wbase;
  if      (group==0) wbase = 0;
  else if (group==1) wbase = 4;
  else if (group==2) wbase = 2;
  else               wbase = 6;
  const ushort* wih = wb + ((size_t)wbase<<20);
  const ushort* whh = wb + ((size_t)(wbase+1)<<20);

  const int  step   = (group < 2) ? s : (s-1);
  const bool have_h = (step > 0);
  const ushort* hsrc = h_ws + ((size_t)group*2 + ((s-1)&1))*(BB*HH);

  // x-half A source
  const float*  xsf = nullptr;
  const ushort* xsb = nullptr;
  if (group == 0){ if (XBF) xsb = xb + (size_t)s*(BB*HH); else xsf = xf + (size_t)s*(BB*HH); }
  else if (group == 1){ if (XBF) xsb = xb + (size_t)(TS-1-s)*(BB*HH); else xsf = xf + (size_t)(TS-1-s)*(BB*HH); }
  else xsb = h_ws + ((size_t)(group-2)*2 + ((s-1)&1))*(BB*HH);

  // B rows (gate-striped): tile0 = {i,f}, tile1 = {g,o}
  const int r0 = ((n>>3)  )*512 + w*8 + (n&7);
  const int r1 = ((n>>3)+2)*512 + w*8 + (n&7);

  const int arow = wv*16 + n;
  const size_t aoff  = (size_t)arow*HH + q*8;
  const size_t b0off = (size_t)r0*HH + q*8;
  const size_t b1off = (size_t)r1*HH + q*8;

  f32x4 acc0 = {0.f,0.f,0.f,0.f};
  f32x4 acc1 = {0.f,0.f,0.f,0.f};

#pragma unroll
  for (int kk=0; kk<16; ++kk){
    sh8 a;
    if (XBF || group >= 2) a = *(const sh8*)(xsb + aoff + kk*32);
    else                   a = ld_cvt8(xsf + aoff + kk*32);
    sh8 b0 = *(const sh8*)(wih + b0off + kk*32);
    sh8 b1 = *(const sh8*)(wih + b1off + kk*32);
    acc0 = __builtin_amdgcn_mfma_f32_16x16x32_bf16(a, b0, acc0, 0, 0, 0);
    acc1 = __builtin_amdgcn_mfma_f32_16x16x32_bf16(a, b1, acc1, 0, 0, 0);
  }
  if (have_h){
#pragma unroll
    for (int kk=0; kk<16; ++kk){
      sh8 a  = *(const sh8*)(hsrc + aoff  + kk*32);
      sh8 b0 = *(const sh8*)(whh  + b0off + kk*32);
      sh8 b1 = *(const sh8*)(whh  + b1off + kk*32);
      acc0 = __builtin_amdgcn_mfma_f32_16x16x32_bf16(a, b0, acc0, 0, 0, 0);
      acc1 = __builtin_amdgcn_mfma_f32_16x16x32_bf16(a, b1, acc1, 0, 0, 0);
    }
  }

  ushort* hdst = h_ws + ((size_t)group*2 + (s&1))*(BB*HH);
  float*  cpt  = c_ws + (size_t)group*(BB*HH);
  const bool low = (n < 8);
  const int  col = w*8 + (n&7);

#pragma unroll
  for (int r=0; r<4; ++r){
    float v0 = acc0[r], v1 = acc1[r];
    float p0 = __shfl_xor(v0, 8, 64);
    float p1 = __shfl_xor(v1, 8, 64);
    if (low){
      const int row = wv*16 + q*4 + r;              // C/D: row = 4q+reg
      const float iv=v0, fv=p0, gv=v1, ov=p1;
      float cold = have_h ? cpt[(size_t)row*HH + col] : 0.f;
      float cn = sigm(fv)*cold + sigm(iv)*tanh_(gv);
      float hn = sigm(ov)*tanh_(cn);
      cpt[(size_t)row*HH + col] = cn;
      hdst[(size_t)row*HH + col] = f2bf(hn);

      if (group == 2){                               // fwd out, t = s-1
        out[((size_t)(s-1)*BB + row)*1024 + col] = hn;
      } else if (group == 3){                        // bwd out, t = 1024-s
        out[((size_t)(TS-s)*BB + row)*1024 + 512 + col] = hn;
      }

      bool cap = false; size_t hoff = 0;
      if      (group==0 && s==TS-1){ cap=true; hoff = HOFF + (size_t)row*1024 + col; }
      else if (group==1 && s==0)   { cap=true; hoff = HOFF + (size_t)row*1024 + 512 + col; }
      else if (group==2 && s==TS)  { cap=true; hoff = HOFF + (size_t)(BB+row)*1024 + col; }
      else if (group==3 && s==1)   { cap=true; hoff = HOFF + (size_t)(BB+row)*1024 + 512 + col; }
      if (cap){
        out[hoff] = hn;
        out[hoff + HC_DELTA] = cn;
      }
    }
  }
}

extern "C" void kernel_launch(void* const* d_in, const int* in_sizes, int n_in,
                              void* d_out, int out_size, void* d_ws, size_t ws_size,
                              hipStream_t stream)
{
  const float* x = (const float*)d_in[0];
  const float* W[8];
  for (int i = 0; i < 8; ++i) W[i] = (const float*)d_in[i+1];
  float* out = (float*)d_out;

  // ws layout: c fp32 [4][64][512] (512KB) | h bf16 [4][2][64][512] (512KB)
  //            | wb bf16 8x2048x512 (16MB) | xb bf16 1024x64x512 (64MB, optional)
  char* ws = (char*)d_ws;
  float*  c_ws = (float*)ws;
  ushort* h_ws = (ushort*)(ws + 524288);
  ushort* wb   = (ushort*)(ws + 1048576);
  ushort* xb   = (ushort*)(ws + 1048576 + 16777216);
  const bool xbf = ws_size >= (1048576ull + 16777216ull + 67108864ull);

  cvt_w<<<dim3(8192), dim3(256), 0, stream>>>(W[0],W[1],W[2],W[3],W[4],W[5],W[6],W[7], wb);
  if (xbf) cvt_x<<<dim3(32768), dim3(256), 0, stream>>>(x, xb);

  for (int s = 0; s <= TS; ++s){
    if (xbf)
      lstm_slot<true ><<<dim3(256), dim3(256), 0, stream>>>(x, xb, wb, out, c_ws, h_ws, s);
    else
      lstm_slot<false><<<dim3(256), dim3(256), 0, stream>>>(x, xb, wb, out, c_ws, h_ws, s);
  }
}